// Round 1
// baseline (2056.952 us; speedup 1.0000x reference)
//
#include <hip/hip_runtime.h>
#include <hip/hip_bf16.h>
#include <math.h>

#define FN 128      // F_NODE
#define FE 64       // F_EDGE
#define EPS 1e-5f

__device__ __forceinline__ float bf2f(unsigned int u_low16) {
    union { unsigned int i; float f; } v; v.i = u_low16 << 16; return v.f;
}
__device__ __forceinline__ unsigned short f2bf(float f) {
    union { float f; unsigned int i; } v; v.f = f;
    unsigned int r = v.i + 0x7FFFu + ((v.i >> 16) & 1u);
    return (unsigned short)(r >> 16);
}

// ---------------------------------------------------------------------------
// Degree counts: cnt[dst] += 1  (f32 exact for small integer counts)
// ---------------------------------------------------------------------------
__global__ void count_kernel(const int* __restrict__ edst, float* __restrict__ cnt, int ne) {
    int e = blockIdx.x * 256 + threadIdx.x;
    if (e < ne) atomicAdd(&cnt[edst[e]], 1.0f);
}

// ---------------------------------------------------------------------------
// Node GEMM: A[n, 512] = X[n,128] @ [Wf(0:128) | Wf(128:256) | Ws(0:128) | Ws(128:256)]
// stored bf16.  Block: 128 rows x 64 cols, 256 threads, each 8x4 outputs.
// ---------------------------------------------------------------------------
__global__ __launch_bounds__(256) void node_gemm(
    const float* __restrict__ X, const float* __restrict__ Wf,
    const float* __restrict__ Ws, unsigned short* __restrict__ A, int nnodes)
{
    __shared__ float Xs[16][129];
    __shared__ float Bs[16][68];
    const int t = threadIdx.x;
    const int m0 = blockIdx.x * 128;
    const int c0 = blockIdx.y * 64;          // 0..511 in steps of 64
    const int part = c0 >> 7;                // 0..3
    const int cp0 = c0 & 127;
    const float* Bsrc = ((part < 2) ? Wf : Ws) + (part & 1) * 128 * 128 + cp0;
    const int tm = t >> 4, tn = t & 15;
    float acc[8][4];
#pragma unroll
    for (int i = 0; i < 8; i++)
#pragma unroll
        for (int j = 0; j < 4; j++) acc[i][j] = 0.0f;

    for (int k0 = 0; k0 < 128; k0 += 16) {
        {   // stage X tile (transposed) : rows m0..m0+127, k k0..k0+15
            int ml = t & 127;
            int kq0 = (t >> 7) * 2;
#pragma unroll
            for (int q = 0; q < 2; q++) {
                int kq = kq0 + q;
                float4 v = make_float4(0.f, 0.f, 0.f, 0.f);
                int m = m0 + ml;
                if (m < nnodes) v = *(const float4*)(X + (size_t)m * FN + k0 + kq * 4);
                Xs[kq * 4 + 0][ml] = v.x; Xs[kq * 4 + 1][ml] = v.y;
                Xs[kq * 4 + 2][ml] = v.z; Xs[kq * 4 + 3][ml] = v.w;
            }
            // stage B tile [16][64]
            int kk = t >> 4, j4 = (t & 15) * 4;
            float4 b = *(const float4*)(Bsrc + (size_t)(k0 + kk) * FN + j4);
            Bs[kk][j4 + 0] = b.x; Bs[kk][j4 + 1] = b.y;
            Bs[kk][j4 + 2] = b.z; Bs[kk][j4 + 3] = b.w;
        }
        __syncthreads();
#pragma unroll
        for (int kk = 0; kk < 16; kk++) {
            float xv[8], bv[4];
#pragma unroll
            for (int i = 0; i < 8; i++) xv[i] = Xs[kk][tm * 8 + i];
#pragma unroll
            for (int j = 0; j < 4; j++) bv[j] = Bs[kk][tn * 4 + j];
#pragma unroll
            for (int i = 0; i < 8; i++)
#pragma unroll
                for (int j = 0; j < 4; j++) acc[i][j] = fmaf(xv[i], bv[j], acc[i][j]);
        }
        __syncthreads();
    }
#pragma unroll
    for (int i = 0; i < 8; i++) {
        int m = m0 + tm * 8 + i;
        if (m < nnodes) {
            size_t base = (size_t)m * 512 + c0 + tn * 4;
#pragma unroll
            for (int j = 0; j < 4; j++) A[base + j] = f2bf(acc[i][j]);
        }
    }
}

// ---------------------------------------------------------------------------
// Fused edge kernel.  Block = 256 thr = 4 waves; each wave owns 64 edges
// (edge-per-lane).  Per 32-col chunk: facc/sacc = bias + gathered node terms
// (bf16 A-table), then on-the-fly edge GEMM (W rows 256..319, wave-uniform
// loads -> scalar), activations, stage msg in LDS, wave-coalesced atomics.
// ---------------------------------------------------------------------------
__global__ __launch_bounds__(256) void edge_kernel(
    const unsigned short* __restrict__ A, const float* __restrict__ EA,
    const int* __restrict__ esrc, const int* __restrict__ edst,
    const float* __restrict__ Wf, const float* __restrict__ Ws,
    const float* __restrict__ bfv, const float* __restrict__ bsv,
    float* __restrict__ summed, int nedges)
{
    __shared__ unsigned short ea_s[4][64][68];   // bf16 edge_attr tile per wave
    __shared__ unsigned short msgb[4][64][34];   // bf16 msg chunk per wave

    const int w = threadIdx.x >> 6, lane = threadIdx.x & 63;
    const int ebase = blockIdx.x * 256 + w * 64;
    int e = ebase + lane;
    bool valid = (e < nedges);
    int eC = valid ? e : (nedges - 1);
    const int mydst = edst[eC];
    const int mysrc = esrc[eC];

    // ---- stage edge_attr tile [64 edges][64] f32 -> bf16 LDS ----
#pragma unroll 4
    for (int it = 0; it < 16; it++) {
        int row = it * 4 + (lane >> 4);
        int q = lane & 15;
        int rowE = ebase + row; if (rowE >= nedges) rowE = nedges - 1;
        float4 v = *(const float4*)(EA + (size_t)rowE * FE + q * 4);
        unsigned int lo = (unsigned int)f2bf(v.x) | ((unsigned int)f2bf(v.y) << 16);
        unsigned int hi = (unsigned int)f2bf(v.z) | ((unsigned int)f2bf(v.w) << 16);
        *(uint2*)&ea_s[w][row][q * 4] = make_uint2(lo, hi);
    }
    __syncthreads();

    for (int c0 = 0; c0 < FN; c0 += 32) {
        float facc[32], sacc[32];
#pragma unroll
        for (int j = 0; j < 32; j++) { facc[j] = bfv[c0 + j]; sacc[j] = bsv[c0 + j]; }

        // ---- gather node terms from bf16 A-table ----
        const unsigned short* Adf = A + (size_t)mydst * 512 + c0;
        const unsigned short* Asf = A + (size_t)mysrc * 512 + 128 + c0;
        const unsigned short* Ads = A + (size_t)mydst * 512 + 256 + c0;
        const unsigned short* Ass = A + (size_t)mysrc * 512 + 384 + c0;
#pragma unroll
        for (int q = 0; q < 4; q++) {
            uint4 g0 = *(const uint4*)(const void*)(Adf + q * 8);
            uint4 g1 = *(const uint4*)(const void*)(Asf + q * 8);
            uint4 g2 = *(const uint4*)(const void*)(Ads + q * 8);
            uint4 g3 = *(const uint4*)(const void*)(Ass + q * 8);
            unsigned int u0[4] = { g0.x, g0.y, g0.z, g0.w };
            unsigned int u1[4] = { g1.x, g1.y, g1.z, g1.w };
            unsigned int u2[4] = { g2.x, g2.y, g2.z, g2.w };
            unsigned int u3[4] = { g3.x, g3.y, g3.z, g3.w };
#pragma unroll
            for (int r = 0; r < 4; r++) {
                int j = q * 8 + r * 2;
                facc[j]     += bf2f(u0[r] & 0xffffu) + bf2f(u1[r] & 0xffffu);
                facc[j + 1] += bf2f(u0[r] >> 16)     + bf2f(u1[r] >> 16);
                sacc[j]     += bf2f(u2[r] & 0xffffu) + bf2f(u3[r] & 0xffffu);
                sacc[j + 1] += bf2f(u2[r] >> 16)     + bf2f(u3[r] >> 16);
            }
        }

        // ---- on-the-fly edge-part GEMM: W rows 256..319, cols c0..c0+31 ----
        for (int k = 0; k < FE; k++) {
            float eav = bf2f((unsigned int)ea_s[w][lane][k]);
            const float* wfp = Wf + (size_t)(256 + k) * FN + c0;   // uniform addr
            const float* wsp = Ws + (size_t)(256 + k) * FN + c0;   // uniform addr
#pragma unroll
            for (int j = 0; j < 32; j++) {
                facc[j] = fmaf(eav, wfp[j], facc[j]);
                sacc[j] = fmaf(eav, wsp[j], sacc[j]);
            }
        }

        // ---- activations: sigmoid(f) * softplus(s) ----
#pragma unroll
        for (int j = 0; j < 32; j++) {
            float f = facc[j], s = sacc[j];
            float sig = 1.0f / (1.0f + __expf(-f));
            float sp = fmaxf(s, 0.0f) + log1pf(__expf(-fabsf(s)));
            float m = sig * sp;
            if (!valid) m = 0.0f;
            msgb[w][lane][j] = f2bf(m);
        }
        __syncthreads();

        // ---- wave-coalesced atomic scatter: 2 edges x 32 cols per instr ----
#pragma unroll 8
        for (int it = 0; it < 32; it++) {
            int e2 = it * 2 + (lane >> 5);
            int cc = lane & 31;
            int d2 = __shfl(mydst, e2);
            float mval = bf2f((unsigned int)msgb[w][e2][cc]);
            atomicAdd(&summed[(size_t)d2 * FN + c0 + cc], mval);
        }
        __syncthreads();
    }
}

// ---------------------------------------------------------------------------
// Finalize: mean aggregate, BN(eval), residual.  (xin may alias out: same-idx)
// ---------------------------------------------------------------------------
__global__ __launch_bounds__(256) void finalize_kernel(
    const float* __restrict__ summed, const float* __restrict__ cnt,
    const float* xin,
    const float* __restrict__ gamma, const float* __restrict__ beta,
    const float* __restrict__ rmean, const float* __restrict__ rvar,
    float* out, int nnodes)
{
    int idx = blockIdx.x * 256 + threadIdx.x;
    if (idx >= nnodes * FN) return;
    int n = idx >> 7, c = idx & (FN - 1);
    float mean = summed[idx] / fmaxf(cnt[n], 1.0f);
    float y = (mean - rmean[c]) * rsqrtf(rvar[c] + EPS) * gamma[c] + beta[c] + xin[idx];
    out[idx] = y;
}

// ---------------------------------------------------------------------------
extern "C" void kernel_launch(void* const* d_in, const int* in_sizes, int n_in,
                              void* d_out, int out_size, void* d_ws, size_t ws_size,
                              hipStream_t stream)
{
    const float* x    = (const float*)d_in[0];
    const int*   eidx = (const int*)d_in[1];
    const float* ea   = (const float*)d_in[2];
    const float* Wf1 = (const float*)d_in[3],  * bf1 = (const float*)d_in[4];
    const float* Ws1 = (const float*)d_in[5],  * bs1 = (const float*)d_in[6];
    const float* g1  = (const float*)d_in[7],  * be1 = (const float*)d_in[8];
    const float* rm1 = (const float*)d_in[9],  * rv1 = (const float*)d_in[10];
    const float* Wf2 = (const float*)d_in[11], * bf2 = (const float*)d_in[12];
    const float* Ws2 = (const float*)d_in[13], * bs2 = (const float*)d_in[14];
    const float* g2  = (const float*)d_in[15], * be2 = (const float*)d_in[16];
    const float* rm2 = (const float*)d_in[17], * rv2 = (const float*)d_in[18];
    float* out = (float*)d_out;

    const int NN = in_sizes[0] / FN;       // 50000
    const int NE = in_sizes[2] / FE;       // 800000
    const int* esrc = eidx;
    const int* edst = eidx + NE;

    // workspace layout
    unsigned short* A  = (unsigned short*)d_ws;                       // NN*512*2  = 51.2 MB
    float* summed      = (float*)((char*)d_ws + (size_t)NN * 512 * 2);// NN*128*4  = 25.6 MB
    float* cnt         = (float*)((char*)summed + (size_t)NN * FN * 4);// NN*4

    const int egrid = (NE + 255) / 256;
    const int ngrid = (NN + 127) / 128;
    const int fgrid = (NN * FN + 255) / 256;

    hipMemsetAsync(cnt, 0, (size_t)NN * 4, stream);
    hipMemsetAsync(summed, 0, (size_t)NN * FN * 4, stream);
    count_kernel<<<egrid, 256, 0, stream>>>(edst, cnt, NE);

    // ---- layer 1 ----
    node_gemm<<<dim3(ngrid, 8), 256, 0, stream>>>(x, Wf1, Ws1, A, NN);
    edge_kernel<<<egrid, 256, 0, stream>>>(A, ea, esrc, edst, Wf1, Ws1, bf1, bs1, summed, NE);
    finalize_kernel<<<fgrid, 256, 0, stream>>>(summed, cnt, x, g1, be1, rm1, rv1, out, NN);

    // ---- layer 2 (input = d_out, in-place residual) ----
    hipMemsetAsync(summed, 0, (size_t)NN * FN * 4, stream);
    node_gemm<<<dim3(ngrid, 8), 256, 0, stream>>>(out, Wf2, Ws2, A, NN);
    edge_kernel<<<egrid, 256, 0, stream>>>(A, ea, esrc, edst, Wf2, Ws2, bf2, bs2, summed, NE);
    finalize_kernel<<<fgrid, 256, 0, stream>>>(summed, cnt, out, g2, be2, rm2, rv2, out, NN);
}

// Round 2
// 1394.408 us; speedup vs baseline: 1.4751x; 1.4751x over previous
//
#include <hip/hip_runtime.h>
#include <math.h>

#define FN 128      // F_NODE
#define FE 64       // F_EDGE
#define EPS 1e-5f

typedef __attribute__((ext_vector_type(8))) short bf16x8;
typedef __attribute__((ext_vector_type(4))) float f32x4;

__device__ __forceinline__ float bf2f(unsigned int u_low16) {
    union { unsigned int i; float f; } v; v.i = u_low16 << 16; return v.f;
}
__device__ __forceinline__ unsigned short f2bf(float f) {
    union { float f; unsigned int i; } v; v.f = f;
    unsigned int r = v.i + 0x7FFFu + ((v.i >> 16) & 1u);
    return (unsigned short)(r >> 16);
}

// ---------------------------------------------------------------------------
__global__ void count_kernel(const int* __restrict__ edst, float* __restrict__ cnt, int ne) {
    int e = blockIdx.x * 256 + threadIdx.x;
    if (e < ne) atomicAdd(&cnt[edst[e]], 1.0f);
}

// ---------------------------------------------------------------------------
// Node GEMM: A[n, 512] = X[n,128] @ [Wf(0:128) | Wf(128:256) | Ws(0:128) | Ws(128:256)]
// ---------------------------------------------------------------------------
__global__ __launch_bounds__(256) void node_gemm(
    const float* __restrict__ X, const float* __restrict__ Wf,
    const float* __restrict__ Ws, unsigned short* __restrict__ A, int nnodes)
{
    __shared__ float Xs[16][129];
    __shared__ float Bs[16][68];
    const int t = threadIdx.x;
    const int m0 = blockIdx.x * 128;
    const int c0 = blockIdx.y * 64;
    const int part = c0 >> 7;
    const int cp0 = c0 & 127;
    const float* Bsrc = ((part < 2) ? Wf : Ws) + (part & 1) * 128 * 128 + cp0;
    const int tm = t >> 4, tn = t & 15;
    float acc[8][4];
#pragma unroll
    for (int i = 0; i < 8; i++)
#pragma unroll
        for (int j = 0; j < 4; j++) acc[i][j] = 0.0f;

    for (int k0 = 0; k0 < 128; k0 += 16) {
        {
            int ml = t & 127;
            int kq0 = (t >> 7) * 2;
#pragma unroll
            for (int q = 0; q < 2; q++) {
                int kq = kq0 + q;
                float4 v = make_float4(0.f, 0.f, 0.f, 0.f);
                int m = m0 + ml;
                if (m < nnodes) v = *(const float4*)(X + (size_t)m * FN + k0 + kq * 4);
                Xs[kq * 4 + 0][ml] = v.x; Xs[kq * 4 + 1][ml] = v.y;
                Xs[kq * 4 + 2][ml] = v.z; Xs[kq * 4 + 3][ml] = v.w;
            }
            int kk = t >> 4, j4 = (t & 15) * 4;
            float4 b = *(const float4*)(Bsrc + (size_t)(k0 + kk) * FN + j4);
            Bs[kk][j4 + 0] = b.x; Bs[kk][j4 + 1] = b.y;
            Bs[kk][j4 + 2] = b.z; Bs[kk][j4 + 3] = b.w;
        }
        __syncthreads();
#pragma unroll
        for (int kk = 0; kk < 16; kk++) {
            float xv[8], bv[4];
#pragma unroll
            for (int i = 0; i < 8; i++) xv[i] = Xs[kk][tm * 8 + i];
#pragma unroll
            for (int j = 0; j < 4; j++) bv[j] = Bs[kk][tn * 4 + j];
#pragma unroll
            for (int i = 0; i < 8; i++)
#pragma unroll
                for (int j = 0; j < 4; j++) acc[i][j] = fmaf(xv[i], bv[j], acc[i][j]);
        }
        __syncthreads();
    }
#pragma unroll
    for (int i = 0; i < 8; i++) {
        int m = m0 + tm * 8 + i;
        if (m < nnodes) {
            size_t base = (size_t)m * 512 + c0 + tn * 4;
#pragma unroll
            for (int j = 0; j < 4; j++) A[base + j] = f2bf(acc[i][j]);
        }
    }
}

// ---------------------------------------------------------------------------
// Fused edge kernel, MFMA edition.
// Block = 256 thr = 4 waves; wave owns 64 edges.
// Edge-part GEMM via mfma_f32_16x16x32_bf16 with A = We^T (M=out cols),
// B = EA^T (N=edges).  C layout: col(lane&15)=edge, row((l>>4)*4+r)=out col.
// ---------------------------------------------------------------------------
__global__ __launch_bounds__(256, 2) void edge_kernel(
    const unsigned short* __restrict__ A, const float* __restrict__ EA,
    const int* __restrict__ esrc, const int* __restrict__ edst,
    const float* __restrict__ Wf, const float* __restrict__ Ws,
    const float* __restrict__ bfv, const float* __restrict__ bsv,
    float* __restrict__ summed, int nedges)
{
    __shared__ unsigned short Wlds[2][128][64];  // [mat][out col][k ^ ((col&7)<<3)]  32 KB
    __shared__ unsigned short Ebuf[4][64][64];   // [wave][edge][col2 ^ ((edge&7)<<3)] 32 KB

    const int t = threadIdx.x;
    const int w = t >> 6, lane = t & 63;
    const int ebase = blockIdx.x * 256 + w * 64;

    // ---- stage We^T (rows 256..319 of Wf/Ws), bf16, swizzled ----
    {
        int col = t & 127;
        int kst = t >> 7;                 // 0 or 1
        int swz = (col & 7) << 3;
#pragma unroll 2
        for (int mat = 0; mat < 2; mat++) {
            const float* Wsrc = (mat == 0 ? Wf : Ws) + 256 * FN + col;
#pragma unroll 8
            for (int k = kst; k < 64; k += 2) {
                Wlds[mat][col][k ^ swz] = f2bf(Wsrc[(size_t)k * FN]);
            }
        }
    }

    int e = ebase + lane;
    bool valid = (e < nedges);
    int eC = valid ? e : (nedges - 1);
    const int mydst = edst[eC];
    const int mysrc = esrc[eC];

    // ---- EA fragments (B operand): lane holds EA[et*16+(l&15)][kk*32+(l>>4)*8 + j] ----
    bf16x8 Eb[4][2];
    {
        const int koff = (lane >> 4) << 3;
#pragma unroll
        for (int et = 0; et < 4; et++) {
            int row = ebase + et * 16 + (lane & 15);
            if (row >= nedges) row = nedges - 1;
            const float* p = EA + (size_t)row * FE + koff;
#pragma unroll
            for (int kk = 0; kk < 2; kk++) {
                float4 v0 = *(const float4*)(p + kk * 32);
                float4 v1 = *(const float4*)(p + kk * 32 + 4);
                bf16x8 b;
                b[0] = (short)f2bf(v0.x); b[1] = (short)f2bf(v0.y);
                b[2] = (short)f2bf(v0.z); b[3] = (short)f2bf(v0.w);
                b[4] = (short)f2bf(v1.x); b[5] = (short)f2bf(v1.y);
                b[6] = (short)f2bf(v1.z); b[7] = (short)f2bf(v1.w);
                Eb[et][kk] = b;
            }
        }
    }
    __syncthreads();   // Wlds ready

    const int rswz = (lane & 7) << 3;

#pragma unroll 1
    for (int cb = 0; cb < 4; cb++) {
        const int c0 = cb * 32;

        // ---- prefetch A-table gathers (used after the MFMA phase) ----
        uint4 ga[4], gb[4], gc[4], gd[4];
        {
            const unsigned short* Adf = A + (size_t)mydst * 512 + c0;
            const unsigned short* Asf = A + (size_t)mysrc * 512 + 128 + c0;
            const unsigned short* Ads = A + (size_t)mydst * 512 + 256 + c0;
            const unsigned short* Ass = A + (size_t)mysrc * 512 + 384 + c0;
#pragma unroll
            for (int q = 0; q < 4; q++) {
                ga[q] = *(const uint4*)(const void*)(Adf + q * 8);
                gb[q] = *(const uint4*)(const void*)(Asf + q * 8);
                gc[q] = *(const uint4*)(const void*)(Ads + q * 8);
                gd[q] = *(const uint4*)(const void*)(Ass + q * 8);
            }
        }

        // ---- MFMA: accF/accS[mt][nt], out col = c0+mt*16+(l>>4)*4+r, edge = nt*16+(l&15) ----
        f32x4 accF[2][4], accS[2][4];
#pragma unroll
        for (int mt = 0; mt < 2; mt++)
#pragma unroll
            for (int nt = 0; nt < 4; nt++) {
                accF[mt][nt] = (f32x4){0.f, 0.f, 0.f, 0.f};
                accS[mt][nt] = (f32x4){0.f, 0.f, 0.f, 0.f};
            }
#pragma unroll
        for (int kk = 0; kk < 2; kk++) {
            bf16x8 aF[2], aS[2];
#pragma unroll
            for (int mt = 0; mt < 2; mt++) {
                int col = c0 + mt * 16 + (lane & 15);
                int kidx = ((kk << 5) + ((lane >> 4) << 3)) ^ ((col & 7) << 3);
                aF[mt] = *(const bf16x8*)&Wlds[0][col][kidx];
                aS[mt] = *(const bf16x8*)&Wlds[1][col][kidx];
            }
#pragma unroll
            for (int mt = 0; mt < 2; mt++)
#pragma unroll
                for (int nt = 0; nt < 4; nt++) {
                    accF[mt][nt] = __builtin_amdgcn_mfma_f32_16x16x32_bf16(
                        aF[mt], Eb[nt][kk], accF[mt][nt], 0, 0, 0);
                    accS[mt][nt] = __builtin_amdgcn_mfma_f32_16x16x32_bf16(
                        aS[mt], Eb[nt][kk], accS[mt][nt], 0, 0, 0);
                }
        }

        __syncthreads();   // previous chunk's scatter reads of Ebuf are done

        // ---- write C frags to Ebuf (b64: 4 consecutive out-cols of one edge) ----
#pragma unroll
        for (int mt = 0; mt < 2; mt++)
#pragma unroll
            for (int nt = 0; nt < 4; nt++) {
                int edge = nt * 16 + (lane & 15);
                int swz = (edge & 7) << 3;
                int c2f = mt * 16 + ((lane >> 4) << 2);
                f32x4 vF = accF[mt][nt], vS = accS[mt][nt];
                unsigned int f01 = (unsigned int)f2bf(vF[0]) | ((unsigned int)f2bf(vF[1]) << 16);
                unsigned int f23 = (unsigned int)f2bf(vF[2]) | ((unsigned int)f2bf(vF[3]) << 16);
                unsigned int s01 = (unsigned int)f2bf(vS[0]) | ((unsigned int)f2bf(vS[1]) << 16);
                unsigned int s23 = (unsigned int)f2bf(vS[2]) | ((unsigned int)f2bf(vS[3]) << 16);
                *(uint2*)&Ebuf[w][edge][c2f ^ swz] = make_uint2(f01, f23);
                *(uint2*)&Ebuf[w][edge][(32 + c2f) ^ swz] = make_uint2(s01, s23);
            }
        __syncthreads();   // C visible to all lanes

        // ---- per-edge phase (lane = edge): bias + edge-GEMM + gathers ----
        float facc[32], sacc[32];
#pragma unroll
        for (int jb = 0; jb < 4; jb++) {
            uint4 uf = *(const uint4*)&Ebuf[w][lane][(jb << 3) ^ rswz];
            uint4 us = *(const uint4*)&Ebuf[w][lane][((jb << 3) + 32) ^ rswz];
            unsigned int wfu[4] = { uf.x, uf.y, uf.z, uf.w };
            unsigned int wsu[4] = { us.x, us.y, us.z, us.w };
#pragma unroll
            for (int r = 0; r < 4; r++) {
                int j = jb * 8 + r * 2;
                facc[j]     = bf2f(wfu[r] & 0xffffu) + bfv[c0 + j];
                facc[j + 1] = bf2f(wfu[r] >> 16)     + bfv[c0 + j + 1];
                sacc[j]     = bf2f(wsu[r] & 0xffffu) + bsv[c0 + j];
                sacc[j + 1] = bf2f(wsu[r] >> 16)     + bsv[c0 + j + 1];
            }
        }
#pragma unroll
        for (int q = 0; q < 4; q++) {
            unsigned int u0[4] = { ga[q].x, ga[q].y, ga[q].z, ga[q].w };
            unsigned int u1[4] = { gb[q].x, gb[q].y, gb[q].z, gb[q].w };
            unsigned int u2[4] = { gc[q].x, gc[q].y, gc[q].z, gc[q].w };
            unsigned int u3[4] = { gd[q].x, gd[q].y, gd[q].z, gd[q].w };
#pragma unroll
            for (int r = 0; r < 4; r++) {
                int j = q * 8 + r * 2;
                facc[j]     += bf2f(u0[r] & 0xffffu) + bf2f(u1[r] & 0xffffu);
                facc[j + 1] += bf2f(u0[r] >> 16)     + bf2f(u1[r] >> 16);
                sacc[j]     += bf2f(u2[r] & 0xffffu) + bf2f(u3[r] & 0xffffu);
                sacc[j + 1] += bf2f(u2[r] >> 16)     + bf2f(u3[r] >> 16);
            }
        }

        // ---- activations + write msg (bf16) back into Ebuf cols 0..31 ----
#pragma unroll
        for (int jb = 0; jb < 4; jb++) {
            unsigned int mw[4];
#pragma unroll
            for (int r = 0; r < 4; r++) {
                int j = jb * 8 + r * 2;
                float f0 = facc[j], s0 = sacc[j];
                float f1 = facc[j + 1], s1 = sacc[j + 1];
                float m0 = (1.0f / (1.0f + __expf(-f0))) *
                           (fmaxf(s0, 0.0f) + log1pf(__expf(-fabsf(s0))));
                float m1 = (1.0f / (1.0f + __expf(-f1))) *
                           (fmaxf(s1, 0.0f) + log1pf(__expf(-fabsf(s1))));
                if (!valid) { m0 = 0.0f; m1 = 0.0f; }
                mw[r] = (unsigned int)f2bf(m0) | ((unsigned int)f2bf(m1) << 16);
            }
            *(uint4*)&Ebuf[w][lane][(jb << 3) ^ rswz] = make_uint4(mw[0], mw[1], mw[2], mw[3]);
        }
        __syncthreads();   // msg visible

        // ---- wave-coalesced atomic scatter: 2 edges x 32 cols per instr ----
#pragma unroll 8
        for (int it = 0; it < 32; it++) {
            int e2 = (it << 1) + (lane >> 5);
            int cc = lane & 31;
            int d2 = __shfl(mydst, e2);
            float mval = bf2f((unsigned int)Ebuf[w][e2][cc ^ ((e2 & 7) << 3)]);
            atomicAdd(&summed[(size_t)d2 * FN + c0 + cc], mval);
        }
    }
}

// ---------------------------------------------------------------------------
__global__ __launch_bounds__(256) void finalize_kernel(
    const float* __restrict__ summed, const float* __restrict__ cnt,
    const float* xin,
    const float* __restrict__ gamma, const float* __restrict__ beta,
    const float* __restrict__ rmean, const float* __restrict__ rvar,
    float* out, int nnodes)
{
    int idx = blockIdx.x * 256 + threadIdx.x;
    if (idx >= nnodes * FN) return;
    int n = idx >> 7, c = idx & (FN - 1);
    float mean = summed[idx] / fmaxf(cnt[n], 1.0f);
    float y = (mean - rmean[c]) * rsqrtf(rvar[c] + EPS) * gamma[c] + beta[c] + xin[idx];
    out[idx] = y;
}

// ---------------------------------------------------------------------------
extern "C" void kernel_launch(void* const* d_in, const int* in_sizes, int n_in,
                              void* d_out, int out_size, void* d_ws, size_t ws_size,
                              hipStream_t stream)
{
    const float* x    = (const float*)d_in[0];
    const int*   eidx = (const int*)d_in[1];
    const float* ea   = (const float*)d_in[2];
    const float* Wf1 = (const float*)d_in[3],  * bf1 = (const float*)d_in[4];
    const float* Ws1 = (const float*)d_in[5],  * bs1 = (const float*)d_in[6];
    const float* g1  = (const float*)d_in[7],  * be1 = (const float*)d_in[8];
    const float* rm1 = (const float*)d_in[9],  * rv1 = (const float*)d_in[10];
    const float* Wf2 = (const float*)d_in[11], * bf2 = (const float*)d_in[12];
    const float* Ws2 = (const float*)d_in[13], * bs2 = (const float*)d_in[14];
    const float* g2  = (const float*)d_in[15], * be2 = (const float*)d_in[16];
    const float* rm2 = (const float*)d_in[17], * rv2 = (const float*)d_in[18];
    float* out = (float*)d_out;

    const int NN = in_sizes[0] / FN;
    const int NE = in_sizes[2] / FE;
    const int* esrc = eidx;
    const int* edst = eidx + NE;

    unsigned short* A  = (unsigned short*)d_ws;                        // NN*512*2
    float* summed      = (float*)((char*)d_ws + (size_t)NN * 512 * 2); // NN*128*4
    float* cnt         = (float*)((char*)summed + (size_t)NN * FN * 4);

    const int egrid = (NE + 255) / 256;
    const int ngrid = (NN + 127) / 128;
    const int fgrid = (NN * FN + 255) / 256;

    hipMemsetAsync(cnt, 0, (size_t)NN * 4, stream);
    hipMemsetAsync(summed, 0, (size_t)NN * FN * 4, stream);
    count_kernel<<<egrid, 256, 0, stream>>>(edst, cnt, NE);

    node_gemm<<<dim3(ngrid, 8), 256, 0, stream>>>(x, Wf1, Ws1, A, NN);
    edge_kernel<<<egrid, 256, 0, stream>>>(A, ea, esrc, edst, Wf1, Ws1, bf1, bs1, summed, NE);
    finalize_kernel<<<fgrid, 256, 0, stream>>>(summed, cnt, x, g1, be1, rm1, rv1, out, NN);

    hipMemsetAsync(summed, 0, (size_t)NN * FN * 4, stream);
    node_gemm<<<dim3(ngrid, 8), 256, 0, stream>>>(out, Wf2, Ws2, A, NN);
    edge_kernel<<<egrid, 256, 0, stream>>>(A, ea, esrc, edst, Wf2, Ws2, bf2, bs2, summed, NE);
    finalize_kernel<<<fgrid, 256, 0, stream>>>(summed, cnt, out, g2, be2, rm2, rv2, out, NN);
}